// Round 4
// baseline (584.397 us; speedup 1.0000x reference)
//
#include <hip/hip_runtime.h>
#include <hip/hip_bf16.h>

// GATv2 x3 layers, MI355X. f32 in/out; edge_index int32.
// R16: R15's lane-per-channel k_score with the LDS transpose split into two
// 16-edge phases over a [64][17] buffer: LDS 34KB -> 17.4KB per block, so
// occupancy goes 4 -> 8 waves/SIMD (VGPR=52). Stride-17 rows keep both the
// b64 writes and b32 reads at <=2-way banking (free). Branch-free inner loop
// (no xd dedupe: duplicate dst rows hit L1 anyway). Keeps head-major xl,
// head-clustered XCD mapping, ea2 scalar stream, W/att hoisted in regs.

#define NN 10000    // nodes
#define NE 200000   // edges
#define ND 128      // node dim (layer 0 input)
#define ED 16       // edge dim
#define CD 64       // conv dim (per head)
#define NH 5        // heads
#define HC 320      // NH*CD
#define EF 210000   // NE + NN (with self loops)
#define EFP 210048  // EF padded to 128 (= WPH*128)
#define NEG 0.2f
#define WPH 1641    // k_score blocks per head = EFP/128
#define TOT2 8205   // WPH*NH
#define G2 8208     // launched blocks (8 XCDs * 1026), guard wk>=TOT2

typedef float f2 __attribute__((ext_vector_type(2)));

// ---- CSR build: count ----
__global__ void k_count(const int* __restrict__ dst, int* __restrict__ deg) {
  int e = blockIdx.x * blockDim.x + threadIdx.x;
  if (e >= NE) return;
  atomicAdd(&deg[dst[e]], 1);
}

// ---- CSR build: exclusive scan (single block, 1024 threads x 10 elems) ----
__global__ __launch_bounds__(1024) void k_scan(const int* __restrict__ deg,
                                               int* __restrict__ rowptr) {
  __shared__ int part[1024];
  int t = threadIdx.x;
  int base = t * 10;
  int local[10];
  int s = 0;
  #pragma unroll
  for (int j = 0; j < 10; j++) {
    int i = base + j;
    local[j] = (i < NN) ? deg[i] : 0;
    s += local[j];
  }
  part[t] = s;
  __syncthreads();
  for (int off = 1; off < 1024; off <<= 1) {
    int v = (t >= off) ? part[t - off] : 0;
    __syncthreads();
    part[t] += v;
    __syncthreads();
  }
  int prefix = (t > 0) ? part[t - 1] : 0;
  #pragma unroll
  for (int j = 0; j < 10; j++) {
    int i = base + j;
    if (i < NN) rowptr[i] = prefix;
    prefix += local[j];
  }
  if (t == 1023) rowptr[NN] = prefix;
}

// ---- CSR build: fill (writes into extended src/dst arrays) ----
__global__ void k_fill(const int* __restrict__ ei, const int* __restrict__ rowptr,
                       int* __restrict__ cursor, int* __restrict__ csr_eid,
                       int* __restrict__ srcx, int* __restrict__ dstx) {
  int e = blockIdx.x * blockDim.x + threadIdx.x;
  if (e >= NE) return;
  int d = ei[NE + e];
  int slot = atomicAdd(&cursor[d], 1);
  int pos = rowptr[d] + slot;
  csr_eid[pos] = e;
  srcx[pos] = ei[e];
  dstx[pos] = d;
}

// ---- extend src/dst with self loops + pad ----
__global__ void k_selfext(int* __restrict__ srcx, int* __restrict__ dstx) {
  int i = blockIdx.x * blockDim.x + threadIdx.x;
  int p = NE + i;
  if (p >= EFP) return;
  int v = (p < EF) ? (p - NE) : 0;
  srcx[p] = v;
  dstx[p] = v;
}

// ---- loop_attr = mean of incoming edge_attr (gather, wave per node) ----
__global__ __launch_bounds__(256) void k_loopattr(const int* __restrict__ csr_eid,
                                                  const int* __restrict__ rowptr,
                                                  const float* __restrict__ eattr,
                                                  float* __restrict__ loop_attr) {
  int wave = threadIdx.x >> 6, lane = threadIdx.x & 63;
  int d = blockIdx.x * 4 + wave;
  if (d >= NN) return;
  int g = lane >> 4, k = lane & 15;
  int b = rowptr[d], n = rowptr[d + 1] - b;
  float s = 0.f;
  for (int i = g; i < n; i += 4)
    s += eattr[(size_t)csr_eid[b + i] * ED + k];
  s += __shfl_xor(s, 16, 64);
  s += __shfl_xor(s, 32, 64);
  if (g == 0) loop_attr[d * ED + k] = s / fmaxf((float)n, 1.0f);
}

// ---- ea2: pair-interleaved edge attrs over ALL EFP positions ----
// ea2[(p>>1)*32 + 2*k + (p&1)] = attr(p)[k]; attr = eattr[eid] | loop_attr | 0
__global__ void k_ea2(const int* __restrict__ csr_eid, const float* __restrict__ eattr,
                      const float* __restrict__ loop_attr, float* __restrict__ ea2) {
  int idx = blockIdx.x * blockDim.x + threadIdx.x;  // p*16 + k
  if (idx >= EFP * ED) return;
  int p = idx >> 4, k = idx & 15;
  float v;
  if (p < NE)      v = eattr[(size_t)csr_eid[p] * ED + k];
  else if (p < EF) v = loop_attr[(size_t)(p - NE) * ED + k];
  else             v = 0.f;
  ea2[((size_t)(p >> 1) * 32) + 2 * k + (p & 1)] = v;
}

// ---- xl = h @ Wl + bl  (no LDS; h rows via uniform broadcast loads) ----
// Output layout: head-major xl[h][node][c], h slice = NN*CD floats (2.56MB).
template <int D>
__global__ __launch_bounds__(320) void k_xl(const float* __restrict__ h,
                                            const float* __restrict__ Wl,
                                            const float* __restrict__ bl,
                                            float* __restrict__ xl) {
  constexpr int NPB = 8;
  int node0 = blockIdx.x * NPB;
  int t = threadIdx.x;  // output column 0..319
  float acc[NPB];
  #pragma unroll
  for (int i = 0; i < NPB; i++) acc[i] = 0.f;
  for (int k = 0; k < D; k += 4) {
    float w0 = Wl[(k + 0) * HC + t];
    float w1 = Wl[(k + 1) * HC + t];
    float w2 = Wl[(k + 2) * HC + t];
    float w3 = Wl[(k + 3) * HC + t];
    #pragma unroll
    for (int i = 0; i < NPB; i++) {
      float4 hv = *(const float4*)(h + (size_t)(node0 + i) * D + k);
      acc[i] += hv.x * w0 + hv.y * w1 + hv.z * w2 + hv.w * w3;
    }
  }
  float bv = bl[t];
  int hh = t >> 6, c = t & 63;  // head, channel (CD=64)
  #pragma unroll
  for (int i = 0; i < NPB; i++)
    xl[((size_t)hh * NN + node0 + i) * CD + c] = acc[i] + bv;
}

// ---- scores: WAVE PER 32 EDGES x HEAD, LANE PER CHANNEL ----
// 2 edges packed per f2 lane. xl reads coalesced (row = 256B). W/att in regs.
// ea via uniform (scalar) loads from ea2. Two-phase [64][17] LDS transpose
// for the 64-lane score reduction (17.4KB/block -> 8 waves/SIMD occupancy).
__global__ __launch_bounds__(256) void k_score(
    const int* __restrict__ srcx, const int* __restrict__ dstx,
    const float* __restrict__ ea2, const float* __restrict__ xl,
    const float* __restrict__ We, const float* __restrict__ att,
    float* __restrict__ wP) {
  __shared__ float lds[4][64][17];
  int wk = (blockIdx.x & 7) * 1026 + (blockIdx.x >> 3);  // contiguous per XCD
  if (wk >= TOT2) return;
  int h  = wk / WPH;                                     // uniform
  int lb = wk - h * WPH;
  int wave = __builtin_amdgcn_readfirstlane(threadIdx.x >> 6);
  int lane = threadIdx.x & 63;
  int p0 = lb * 128 + wave * 32;                         // uniform

  // hoist W (16 f2-splat regs via op_sel) and att
  f2 wv[16];
  #pragma unroll
  for (int k = 0; k < 16; k++) {
    float w = We[k * HC + h * CD + lane];
    wv[k] = f2{w, w};
  }
  float a1 = att[h * CD + lane];
  f2 av = f2{a1, a1};
  const float* xh = xl + (size_t)h * NN * CD;  // head slice
  const f2 zero = {0.f, 0.f};

  f2 acc[16];
  #pragma unroll
  for (int i = 0; i < 16; i++) {
    int p = p0 + 2 * i;
    int s0 = srcx[p], s1 = srcx[p + 1];        // uniform -> s_load
    int d0 = dstx[p], d1 = dstx[p + 1];
    const f2* e = (const f2*)(ea2 + (size_t)(p >> 1) * 32);  // uniform
    float xs0 = xh[(size_t)s0 * CD + lane];    // coalesced 256B row
    float xs1 = xh[(size_t)s1 * CD + lane];
    float xd0 = xh[(size_t)d0 * CD + lane];
    float xd1 = xh[(size_t)d1 * CD + lane];
    f2 z = f2{xs0 + xd0, xs1 + xd1};
    #pragma unroll
    for (int k = 0; k < 16; k++)
      z += e[k] * wv[k];                       // v_pk_fma, sgpr-pair operand
    z = __builtin_elementwise_max(z, zero) + NEG * __builtin_elementwise_min(z, zero);
    acc[i] = z * av;
  }

  // two-phase transpose-reduce over [64][17] (both phases <=2-way banked)
  float (*L)[17] = lds[wave];
  int q = lane >> 4, e16 = lane & 15;
  // phase A: edges 0..15 (acc[0..7])
  #pragma unroll
  for (int i = 0; i < 8; i++)
    *(f2*)&L[lane][2 * i] = acc[i];
  float sA = 0.f;
  #pragma unroll
  for (int r = 0; r < 16; r++)
    sA += L[q * 16 + r][e16];
  sA += __shfl_xor(sA, 16, 64);
  sA += __shfl_xor(sA, 32, 64);
  __builtin_amdgcn_wave_barrier();             // pin phase order (no HW cost)
  // phase B: edges 16..31 (acc[8..15])
  #pragma unroll
  for (int i = 0; i < 8; i++)
    *(f2*)&L[lane][2 * i] = acc[8 + i];
  float sB = 0.f;
  #pragma unroll
  for (int r = 0; r < 16; r++)
    sB += L[q * 16 + r][e16];
  sB += __shfl_xor(sB, 16, 64);
  sB += __shfl_xor(sB, 32, 64);

  float sum = (lane < 16) ? sA : sB;           // lane j<32 holds edge j score
  if (lane < 32) {
    float sc = fminf(fmaxf(sum, -60.f), 60.f);
    wP[(size_t)h * EFP + p0 + lane] = __expf(sc);  // coalesced 128B store
  }
}

// ---- aggregation: block per node, wave per head; single pass (no max/exp) --
__global__ __launch_bounds__(320) void k_agg(
    const int* __restrict__ csr_src, const int* __restrict__ rowptr,
    const float* __restrict__ wP, const float* __restrict__ xl,
    const float* __restrict__ bias, float* __restrict__ out) {
  __shared__ float s_v[NH][CD];
  int h = threadIdx.x >> 6, lane = threadIdx.x & 63;
  int d = blockIdx.x;
  int b = rowptr[d], n = rowptr[d + 1] - b;
  const float* sp = wP + (size_t)h * EFP;
  const float* xlh = xl + (size_t)h * NN * CD + lane;  // head-major layout
  // self loop init
  float dn = sp[NE + d];
  float acc = dn * xlh[(size_t)d * CD];
  // edge loop, unroll 4 (uniform w addrs -> scalar loads)
  int p = b, pe = b + n;
  for (; p + 4 <= pe; p += 4) {
    int s0 = csr_src[p], s1 = csr_src[p + 1], s2 = csr_src[p + 2], s3 = csr_src[p + 3];
    float w0 = sp[p], w1 = sp[p + 1], w2 = sp[p + 2], w3 = sp[p + 3];
    float x0 = xlh[(size_t)s0 * CD];
    float x1 = xlh[(size_t)s1 * CD];
    float x2 = xlh[(size_t)s2 * CD];
    float x3 = xlh[(size_t)s3 * CD];
    dn += (w0 + w1) + (w2 + w3);
    acc += w0 * x0 + w1 * x1 + w2 * x2 + w3 * x3;
  }
  for (; p < pe; p++) {
    int s0 = csr_src[p];
    float w0 = sp[p];
    dn += w0;
    acc += w0 * xlh[(size_t)s0 * CD];
  }
  s_v[h][lane] = acc / dn;
  __syncthreads();
  if (h == 0) {
    float v = s_v[0][lane] + s_v[1][lane] + s_v[2][lane] + s_v[3][lane] + s_v[4][lane];
    v = v * (1.0f / NH) + bias[lane];
    v = v > 0.f ? v : expm1f(v);
    out[(size_t)d * CD + lane] = v;
  }
}

static inline size_t aln(size_t x) { return (x + 255) & ~(size_t)255; }

extern "C" void kernel_launch(void* const* d_in, const int* in_sizes, int n_in,
                              void* d_out, int out_size, void* d_ws, size_t ws_size,
                              hipStream_t stream) {
  const float* x = (const float*)d_in[0];
  const int* ei = (const int*)d_in[1];      // [2, NE]: src row then dst row
  const float* eattr = (const float*)d_in[2];

  char* w = (char*)d_ws;
  int* degi      = (int*)w;                 w += aln(NN * 4);
  int* cursor    = (int*)w;                 w += aln(NN * 4);
  int* rowptr    = (int*)w;                 w += aln((NN + 1) * 4);
  int* csr_eid   = (int*)w;                 w += aln((size_t)NE * 4);
  int* srcx      = (int*)w;                 w += aln((size_t)EFP * 4);
  int* dstx      = (int*)w;                 w += aln((size_t)EFP * 4);
  float* loop_attr = (float*)w;             w += aln((size_t)NN * ED * 4);
  float* ea2     = (float*)w;               w += aln((size_t)EFP * ED * 4);
  float* xl      = (float*)w;               w += aln((size_t)NN * HC * 4);
  float* wPbuf   = (float*)w;               w += aln((size_t)NH * EFP * 4);
  float* hbuf    = (float*)w;               w += aln((size_t)NN * CD * 4);

  // graph structure + permuted edge attrs (layer-invariant)
  hipMemsetAsync(degi, 0, NN * 4, stream);
  hipMemsetAsync(cursor, 0, NN * 4, stream);
  k_count<<<(NE + 255) / 256, 256, 0, stream>>>(ei + NE, degi);
  k_scan<<<1, 1024, 0, stream>>>(degi, rowptr);
  k_fill<<<(NE + 255) / 256, 256, 0, stream>>>(ei, rowptr, cursor, csr_eid, srcx, dstx);
  k_selfext<<<(EFP - NE + 255) / 256, 256, 0, stream>>>(srcx, dstx);
  k_loopattr<<<(NN + 3) / 4, 256, 0, stream>>>(csr_eid, rowptr, eattr, loop_attr);
  k_ea2<<<(EFP * ED + 255) / 256, 256, 0, stream>>>(csr_eid, eattr, loop_attr, ea2);

  for (int l = 0; l < 3; l++) {
    const float* Wl  = (const float*)d_in[3 + 5 * l];
    const float* bl  = (const float*)d_in[4 + 5 * l];
    const float* We  = (const float*)d_in[5 + 5 * l];
    const float* att = (const float*)d_in[6 + 5 * l];
    const float* b   = (const float*)d_in[7 + 5 * l];

    if (l == 0) k_xl<ND><<<NN / 8, 320, 0, stream>>>(x, Wl, bl, xl);
    else        k_xl<CD><<<NN / 8, 320, 0, stream>>>(hbuf, Wl, bl, xl);

    k_score<<<G2, 256, 0, stream>>>(srcx, dstx, ea2, xl, We, att, wPbuf);

    float* dst_out = (l < 2) ? hbuf : (float*)d_out;
    k_agg<<<NN, 320, 0, stream>>>(srcx, rowptr, wPbuf, xl, b, dst_out);
  }
}

// Round 6
// 505.880 us; speedup vs baseline: 1.1552x; 1.1552x over previous
//
#include <hip/hip_runtime.h>
#include <hip/hip_bf16.h>

// GATv2 x3 layers, MI355X. f32 in/out; edge_index int32.
// R18: R17 design with ZERO extra workspace (R17's 12.8MB partial buffer
// pushed ws from 35.5MB to 48.3MB -> likely ws overflow -> container fault).
// k_score = R14 exact (per-thread packed-f2 loop, 63.2us measured best).
// k_agg2 = one wave per (head,node), head-clustered XCD mapping (per-XCD xl
// gather working set = one 2.56MB head slice, L2-resident); each wave
// atomicAdds acc/dn into hbuf[d][c] (memset per layer); k_comb applies
// mean+bias+ELU (in-place hbuf for l<2, d_out for l=2).

#define NN 10000    // nodes
#define NE 200000   // edges
#define ND 128      // node dim (layer 0 input)
#define ED 16       // edge dim
#define CD 64       // conv dim (per head)
#define NH 5        // heads
#define HC 320      // NH*CD
#define EF 210000   // NE + NN (with self loops)
#define EFP 210048  // EF padded to 64
#define NEG 0.2f
#define PB 824      // k_score p-blocks per head (824*256 >= EF)
#define TOTB 4120   // PB*NH total k_score blocks = 8 XCDs * 515
#define PERX 515    // k_score work items per XCD
#define NW_AGG 50000   // NH*NN waves
#define BL_AGG 12504   // 8*1563 blocks (4 waves each), guard g>=NW_AGG
#define PERXA 1563     // agg blocks per XCD

typedef float f2 __attribute__((ext_vector_type(2)));

// ---- CSR build: count ----
__global__ void k_count(const int* __restrict__ dst, int* __restrict__ deg) {
  int e = blockIdx.x * blockDim.x + threadIdx.x;
  if (e >= NE) return;
  atomicAdd(&deg[dst[e]], 1);
}

// ---- CSR build: exclusive scan (single block, 1024 threads x 10 elems) ----
__global__ __launch_bounds__(1024) void k_scan(const int* __restrict__ deg,
                                               int* __restrict__ rowptr) {
  __shared__ int part[1024];
  int t = threadIdx.x;
  int base = t * 10;
  int local[10];
  int s = 0;
  #pragma unroll
  for (int j = 0; j < 10; j++) {
    int i = base + j;
    local[j] = (i < NN) ? deg[i] : 0;
    s += local[j];
  }
  part[t] = s;
  __syncthreads();
  for (int off = 1; off < 1024; off <<= 1) {
    int v = (t >= off) ? part[t - off] : 0;
    __syncthreads();
    part[t] += v;
    __syncthreads();
  }
  int prefix = (t > 0) ? part[t - 1] : 0;
  #pragma unroll
  for (int j = 0; j < 10; j++) {
    int i = base + j;
    if (i < NN) rowptr[i] = prefix;
    prefix += local[j];
  }
  if (t == 1023) rowptr[NN] = prefix;
}

// ---- CSR build: fill ----
__global__ void k_fill(const int* __restrict__ ei, const int* __restrict__ rowptr,
                       int* __restrict__ cursor, int* __restrict__ csr_eid,
                       int* __restrict__ csr_src, int* __restrict__ csr_dst) {
  int e = blockIdx.x * blockDim.x + threadIdx.x;
  if (e >= NE) return;
  int d = ei[NE + e];
  int slot = atomicAdd(&cursor[d], 1);
  int pos = rowptr[d] + slot;
  csr_eid[pos] = e;
  csr_src[pos] = ei[e];
  csr_dst[pos] = d;
}

// ---- loop_attr = mean of incoming edge_attr (gather, wave per node) ----
__global__ __launch_bounds__(256) void k_loopattr(const int* __restrict__ csr_eid,
                                                  const int* __restrict__ rowptr,
                                                  const float* __restrict__ eattr,
                                                  float* __restrict__ loop_attr) {
  int wave = threadIdx.x >> 6, lane = threadIdx.x & 63;
  int d = blockIdx.x * 4 + wave;
  if (d >= NN) return;
  int g = lane >> 4, k = lane & 15;
  int b = rowptr[d], n = rowptr[d + 1] - b;
  float s = 0.f;
  for (int i = g; i < n; i += 4)
    s += eattr[(size_t)csr_eid[b + i] * ED + k];
  s += __shfl_xor(s, 16, 64);
  s += __shfl_xor(s, 32, 64);
  if (g == 0) loop_attr[d * ED + k] = s / fmaxf((float)n, 1.0f);
}

// ---- ea_csr[p] = edge attrs permuted into CSR order (real edges only) ----
__global__ void k_eacsr(const int* __restrict__ csr_eid, const float* __restrict__ eattr,
                        float* __restrict__ ea_csr) {
  int idx = blockIdx.x * blockDim.x + threadIdx.x;  // (p, quad)
  if (idx >= NE * 4) return;
  int p = idx >> 2, q = idx & 3;
  const float4* sp = (const float4*)(eattr + (size_t)csr_eid[p] * ED);
  ((float4*)(ea_csr + (size_t)p * ED))[q] = sp[q];
}

// ---- Wpk: channel-pair-interleaved We transpose for packed fp32 ----
// Wpk[((h*32 + cp)*16 + k)*2 + j] = We[k][h*64 + 2*cp + j]
__global__ void k_wet(const float* __restrict__ We, float* __restrict__ Wpk) {
  int i = blockIdx.x * blockDim.x + threadIdx.x;
  if (i >= ED * HC) return;
  int j  = i & 1;
  int k  = (i >> 1) & 15;
  int cp = (i >> 5) & 31;
  int h  = i >> 10;
  Wpk[i] = We[k * HC + h * CD + cp * 2 + j];
}

// ---- xl = h @ Wl + bl  (no LDS; h rows via uniform broadcast loads) ----
// Output layout: head-major xl[h][node][c], h slice = NN*CD floats (2.56MB).
template <int D>
__global__ __launch_bounds__(320) void k_xl(const float* __restrict__ h,
                                            const float* __restrict__ Wl,
                                            const float* __restrict__ bl,
                                            float* __restrict__ xl) {
  constexpr int NPB = 8;
  int node0 = blockIdx.x * NPB;
  int t = threadIdx.x;  // output column 0..319
  float acc[NPB];
  #pragma unroll
  for (int i = 0; i < NPB; i++) acc[i] = 0.f;
  for (int k = 0; k < D; k += 4) {
    float w0 = Wl[(k + 0) * HC + t];
    float w1 = Wl[(k + 1) * HC + t];
    float w2 = Wl[(k + 2) * HC + t];
    float w3 = Wl[(k + 3) * HC + t];
    #pragma unroll
    for (int i = 0; i < NPB; i++) {
      float4 hv = *(const float4*)(h + (size_t)(node0 + i) * D + k);
      acc[i] += hv.x * w0 + hv.y * w1 + hv.z * w2 + hv.w * w3;
    }
  }
  float bv = bl[t];
  int hh = t >> 6, c = t & 63;  // head, channel (CD=64)
  #pragma unroll
  for (int i = 0; i < NPB; i++)
    xl[((size_t)hh * NN + node0 + i) * CD + c] = acc[i] + bv;
}

// ---- scores: ONE THREAD PER (EDGE, HEAD); writes w = exp(clamped score).
// R14 exact: packed-fp32 inner loop, channel pairs in f2 regs, head-clustered
// XCD mapping (per-XCD gather working set ~ one 2.56MB xl head slice).
__global__ __launch_bounds__(256) void k_score(
    const int* __restrict__ csr_src, const int* __restrict__ csr_dst,
    const float* __restrict__ ea_csr, const float* __restrict__ loop_attr,
    const float* __restrict__ xl, const float* __restrict__ Wpk,
    const float* __restrict__ att, float* __restrict__ wP) {
  int bid = blockIdx.x;                       // 0..TOTB-1
  int w = (bid & 7) * PERX + (bid >> 3);      // work item, contiguous per XCD
  int h = w / PB;                             // head (uniform, magic-div)
  int lb = w - h * PB;                        // p-slice within head
  int p = lb * 256 + threadIdx.x;
  if (p >= EF) return;
  int s, d;
  const float* ea;
  if (p < NE) { s = csr_src[p]; d = csr_dst[p]; ea = ea_csr + (size_t)p * ED; }
  else        { s = d = p - NE; ea = loop_attr + (size_t)(p - NE) * ED; }
  float eas[16];
  {
    const float4* q = (const float4*)ea;
    float4 t0 = q[0], t1 = q[1], t2 = q[2], t3 = q[3];
    eas[0] = t0.x;  eas[1] = t0.y;  eas[2] = t0.z;  eas[3] = t0.w;
    eas[4] = t1.x;  eas[5] = t1.y;  eas[6] = t1.z;  eas[7] = t1.w;
    eas[8] = t2.x;  eas[9] = t2.y;  eas[10] = t2.z; eas[11] = t2.w;
    eas[12] = t3.x; eas[13] = t3.y; eas[14] = t3.z; eas[15] = t3.w;
  }
  const float* xsrow = xl + ((size_t)h * NN + s) * CD;
  const float* xdrow = xl + ((size_t)h * NN + d) * CD;
  const f2* wp = (const f2*)Wpk + (size_t)h * (CD / 2) * ED;  // [32 pairs][16 k]
  const f2* ap = (const f2*)(att + (size_t)h * CD);           // pairs contiguous
  f2 sc2 = {0.f, 0.f};
  const f2 zero = {0.f, 0.f};
  #pragma unroll 4
  for (int cb = 0; cb < CD; cb += 4) {  // 2 channel-pairs per iter, 16 iters
    int cp = cb >> 1;
    float4 xs4 = *(const float4*)(xsrow + cb);
    float4 xd4 = *(const float4*)(xdrow + cb);
    const f2* w0 = wp + (size_t)cp * ED;
    const f2* w1 = w0 + ED;
    f2 z0 = f2{xs4.x, xs4.y} + f2{xd4.x, xd4.y};   // v_pk_add_f32
    f2 z1 = f2{xs4.z, xs4.w} + f2{xd4.z, xd4.w};
    #pragma unroll
    for (int k = 0; k < ED; k++) {                 // 2x v_pk_fma_f32 per k
      z0 += w0[k] * eas[k];
      z1 += w1[k] * eas[k];
    }
    // leaky: max(z,0) + NEG*min(z,0)  (packed, branchless, exact)
    z0 = __builtin_elementwise_max(z0, zero) + NEG * __builtin_elementwise_min(z0, zero);
    z1 = __builtin_elementwise_max(z1, zero) + NEG * __builtin_elementwise_min(z1, zero);
    sc2 += z0 * ap[cp];
    sc2 += z1 * ap[cp + 1];
  }
  float sc = sc2.x + sc2.y;
  sc = fminf(fmaxf(sc, -60.f), 60.f);  // clamp never binds for sane inputs
  wP[(size_t)h * EFP + p] = __expf(sc);
}

// ---- aggregation: ONE WAVE PER (HEAD, NODE), head-clustered XCD mapping ----
// Each XCD's xl gather working set ~= one 2.56MB head slice (L2-resident).
// Wave atomicAdds its head's (acc/dn) into accum[d][c] (pre-zeroed hbuf).
__global__ __launch_bounds__(256) void k_agg2(
    const int* __restrict__ csr_src, const int* __restrict__ rowptr,
    const float* __restrict__ wP, const float* __restrict__ xl,
    float* __restrict__ accum) {
  int bid = blockIdx.x;
  int b2 = (bid & 7) * PERXA + (bid >> 3);   // contiguous per XCD
  int wv = threadIdx.x >> 6, lane = threadIdx.x & 63;
  int g = b2 * 4 + wv;                        // global wave id, head-major
  if (g >= NW_AGG) return;
  int h = g / NN;                             // uniform (magic-div)
  int d = g - h * NN;
  int b = rowptr[d], n = rowptr[d + 1] - b;
  const float* sp = wP + (size_t)h * EFP;
  const float* xlh = xl + (size_t)h * NN * CD + lane;  // head slice
  // self loop init
  float dn = sp[NE + d];
  float acc = dn * xlh[(size_t)d * CD];
  // edge loop, unroll 4 (uniform addrs -> scalar loads)
  int p = b, pe = b + n;
  for (; p + 4 <= pe; p += 4) {
    int s0 = csr_src[p], s1 = csr_src[p + 1], s2 = csr_src[p + 2], s3 = csr_src[p + 3];
    float w0 = sp[p], w1 = sp[p + 1], w2 = sp[p + 2], w3 = sp[p + 3];
    float x0 = xlh[(size_t)s0 * CD];
    float x1 = xlh[(size_t)s1 * CD];
    float x2 = xlh[(size_t)s2 * CD];
    float x3 = xlh[(size_t)s3 * CD];
    dn += (w0 + w1) + (w2 + w3);
    acc += w0 * x0 + w1 * x1 + w2 * x2 + w3 * x3;
  }
  for (; p < pe; p++) {
    int s0 = csr_src[p];
    float w0 = sp[p];
    dn += w0;
    acc += w0 * xlh[(size_t)s0 * CD];
  }
  atomicAdd(&accum[(size_t)d * CD + lane], acc / dn);
}

// ---- combine: out[d][c] = elu(accum[d][c]/NH + bias[c]); may be in-place --
__global__ __launch_bounds__(256) void k_comb(const float* accum,
                                              const float* __restrict__ bias,
                                              float* out) {
  int idx = blockIdx.x * blockDim.x + threadIdx.x;  // d*CD + c
  if (idx >= NN * CD) return;
  int c = idx & (CD - 1);
  float v = accum[idx] * (1.0f / NH) + bias[c];
  v = v > 0.f ? v : expm1f(v);
  out[idx] = v;
}

static inline size_t aln(size_t x) { return (x + 255) & ~(size_t)255; }

extern "C" void kernel_launch(void* const* d_in, const int* in_sizes, int n_in,
                              void* d_out, int out_size, void* d_ws, size_t ws_size,
                              hipStream_t stream) {
  const float* x = (const float*)d_in[0];
  const int* ei = (const int*)d_in[1];      // [2, NE]: src row then dst row
  const float* eattr = (const float*)d_in[2];

  char* w = (char*)d_ws;
  int* degi      = (int*)w;                 w += aln(NN * 4);
  int* cursor    = (int*)w;                 w += aln(NN * 4);
  int* rowptr    = (int*)w;                 w += aln((NN + 1) * 4);
  int* csr_eid   = (int*)w;                 w += aln((size_t)NE * 4);
  int* csr_src   = (int*)w;                 w += aln((size_t)NE * 4);
  int* csr_dst   = (int*)w;                 w += aln((size_t)NE * 4);
  float* loop_attr = (float*)w;             w += aln((size_t)NN * ED * 4);
  float* ea_csr  = (float*)w;               w += aln((size_t)NE * ED * 4);
  float* xl      = (float*)w;               w += aln((size_t)NN * HC * 4);
  float* wPbuf   = (float*)w;               w += aln((size_t)NH * EFP * 4);
  float* Wpk     = (float*)w;               w += aln((size_t)ED * HC * 4);
  float* hbuf    = (float*)w;               w += aln((size_t)NN * CD * 4);

  // graph structure + permuted edge attrs (layer-invariant)
  hipMemsetAsync(degi, 0, NN * 4, stream);
  hipMemsetAsync(cursor, 0, NN * 4, stream);
  k_count<<<(NE + 255) / 256, 256, 0, stream>>>(ei + NE, degi);
  k_scan<<<1, 1024, 0, stream>>>(degi, rowptr);
  k_fill<<<(NE + 255) / 256, 256, 0, stream>>>(ei, rowptr, cursor, csr_eid, csr_src, csr_dst);
  k_loopattr<<<(NN + 3) / 4, 256, 0, stream>>>(csr_eid, rowptr, eattr, loop_attr);
  k_eacsr<<<(NE * 4 + 255) / 256, 256, 0, stream>>>(csr_eid, eattr, ea_csr);

  for (int l = 0; l < 3; l++) {
    const float* Wl  = (const float*)d_in[3 + 5 * l];
    const float* bl  = (const float*)d_in[4 + 5 * l];
    const float* We  = (const float*)d_in[5 + 5 * l];
    const float* att = (const float*)d_in[6 + 5 * l];
    const float* b   = (const float*)d_in[7 + 5 * l];

    k_wet<<<(ED * HC + 255) / 256, 256, 0, stream>>>(We, Wpk);
    if (l == 0) k_xl<ND><<<NN / 8, 320, 0, stream>>>(x, Wl, bl, xl);
    else        k_xl<CD><<<NN / 8, 320, 0, stream>>>(hbuf, Wl, bl, xl);

    // hbuf is free now (k_xl consumed it) -> becomes the head-sum accumulator
    hipMemsetAsync(hbuf, 0, (size_t)NN * CD * 4, stream);

    k_score<<<TOTB, 256, 0, stream>>>(csr_src, csr_dst, ea_csr, loop_attr,
                                      xl, Wpk, att, wPbuf);

    k_agg2<<<BL_AGG, 256, 0, stream>>>(csr_src, rowptr, wPbuf, xl, hbuf);

    float* dst_out = (l < 2) ? hbuf : (float*)d_out;
    k_comb<<<(NN * CD + 255) / 256, 256, 0, stream>>>(hbuf, b, dst_out);
  }
}

// Round 7
// 471.270 us; speedup vs baseline: 1.2400x; 1.0734x over previous
//
#include <hip/hip_runtime.h>
#include <hip/hip_bf16.h>

// GATv2 x3 layers, MI355X. f32 in/out; edge_index int32.
// R19: node-major xl [n][HC] restored (R12's agg locality: per-edge the
// 5-wave agg block reads one contiguous 1280B row; k_xl stores contiguous).
// k_score keeps R14 packed-f2 body + head-clustered XCD mapping — L2
// residency is line-based, so node-major gives the same 2.56MB/head line
// working set; only row addressing changes (xl + s*HC + h*CD).
// Fused k_agg (R12-style: block per node, wave per head, LDS head-reduce,
// bias+ELU) replaces memset+agg2+comb: 2 fewer dispatches/layer, no atomics.
// k_loopattr now reads ea_csr contiguously (CSR order) after k_eacsr.

#define NN 10000    // nodes
#define NE 200000   // edges
#define ND 128      // node dim (layer 0 input)
#define ED 16       // edge dim
#define CD 64       // conv dim (per head)
#define NH 5        // heads
#define HC 320      // NH*CD
#define EF 210000   // NE + NN (with self loops)
#define EFP 210048  // EF padded to 64
#define NEG 0.2f
#define PB 824      // k_score p-blocks per head (824*256 >= EF)
#define TOTB 4120   // PB*NH total k_score blocks = 8 XCDs * 515
#define PERX 515    // k_score work items per XCD

typedef float f2 __attribute__((ext_vector_type(2)));

// ---- CSR build: count ----
__global__ void k_count(const int* __restrict__ dst, int* __restrict__ deg) {
  int e = blockIdx.x * blockDim.x + threadIdx.x;
  if (e >= NE) return;
  atomicAdd(&deg[dst[e]], 1);
}

// ---- CSR build: exclusive scan (single block, 1024 threads x 10 elems) ----
__global__ __launch_bounds__(1024) void k_scan(const int* __restrict__ deg,
                                               int* __restrict__ rowptr) {
  __shared__ int part[1024];
  int t = threadIdx.x;
  int base = t * 10;
  int local[10];
  int s = 0;
  #pragma unroll
  for (int j = 0; j < 10; j++) {
    int i = base + j;
    local[j] = (i < NN) ? deg[i] : 0;
    s += local[j];
  }
  part[t] = s;
  __syncthreads();
  for (int off = 1; off < 1024; off <<= 1) {
    int v = (t >= off) ? part[t - off] : 0;
    __syncthreads();
    part[t] += v;
    __syncthreads();
  }
  int prefix = (t > 0) ? part[t - 1] : 0;
  #pragma unroll
  for (int j = 0; j < 10; j++) {
    int i = base + j;
    if (i < NN) rowptr[i] = prefix;
    prefix += local[j];
  }
  if (t == 1023) rowptr[NN] = prefix;
}

// ---- CSR build: fill ----
__global__ void k_fill(const int* __restrict__ ei, const int* __restrict__ rowptr,
                       int* __restrict__ cursor, int* __restrict__ csr_eid,
                       int* __restrict__ csr_src, int* __restrict__ csr_dst) {
  int e = blockIdx.x * blockDim.x + threadIdx.x;
  if (e >= NE) return;
  int d = ei[NE + e];
  int slot = atomicAdd(&cursor[d], 1);
  int pos = rowptr[d] + slot;
  csr_eid[pos] = e;
  csr_src[pos] = ei[e];
  csr_dst[pos] = d;
}

// ---- ea_csr[p] = edge attrs permuted into CSR order (real edges only) ----
__global__ void k_eacsr(const int* __restrict__ csr_eid, const float* __restrict__ eattr,
                        float* __restrict__ ea_csr) {
  int idx = blockIdx.x * blockDim.x + threadIdx.x;  // (p, quad)
  if (idx >= NE * 4) return;
  int p = idx >> 2, q = idx & 3;
  const float4* sp = (const float4*)(eattr + (size_t)csr_eid[p] * ED);
  ((float4*)(ea_csr + (size_t)p * ED))[q] = sp[q];
}

// ---- loop_attr = mean of incoming edge_attr; reads ea_csr CONTIGUOUSLY ----
__global__ __launch_bounds__(256) void k_loopattr(const float* __restrict__ ea_csr,
                                                  const int* __restrict__ rowptr,
                                                  float* __restrict__ loop_attr) {
  int wave = threadIdx.x >> 6, lane = threadIdx.x & 63;
  int d = blockIdx.x * 4 + wave;
  if (d >= NN) return;
  int g = lane >> 4, k = lane & 15;
  int b = rowptr[d], n = rowptr[d + 1] - b;
  float s = 0.f;
  for (int i = g; i < n; i += 4)
    s += ea_csr[(size_t)(b + i) * ED + k];   // contiguous CSR rows
  s += __shfl_xor(s, 16, 64);
  s += __shfl_xor(s, 32, 64);
  if (g == 0) loop_attr[d * ED + k] = s / fmaxf((float)n, 1.0f);
}

// ---- Wpk: channel-pair-interleaved We transpose for packed fp32 ----
// Wpk[((h*32 + cp)*16 + k)*2 + j] = We[k][h*64 + 2*cp + j]
__global__ void k_wet(const float* __restrict__ We, float* __restrict__ Wpk) {
  int i = blockIdx.x * blockDim.x + threadIdx.x;
  if (i >= ED * HC) return;
  int j  = i & 1;
  int k  = (i >> 1) & 15;
  int cp = (i >> 5) & 31;
  int h  = i >> 10;
  Wpk[i] = We[k * HC + h * CD + cp * 2 + j];
}

// ---- xl = h @ Wl + bl  (no LDS; h rows via uniform broadcast loads) ----
// Node-major output xl[node][hc] (contiguous 1280B rows).
template <int D>
__global__ __launch_bounds__(320) void k_xl(const float* __restrict__ h,
                                            const float* __restrict__ Wl,
                                            const float* __restrict__ bl,
                                            float* __restrict__ xl) {
  constexpr int NPB = 8;
  int node0 = blockIdx.x * NPB;
  int t = threadIdx.x;  // output column 0..319
  float acc[NPB];
  #pragma unroll
  for (int i = 0; i < NPB; i++) acc[i] = 0.f;
  for (int k = 0; k < D; k += 4) {
    float w0 = Wl[(k + 0) * HC + t];
    float w1 = Wl[(k + 1) * HC + t];
    float w2 = Wl[(k + 2) * HC + t];
    float w3 = Wl[(k + 3) * HC + t];
    #pragma unroll
    for (int i = 0; i < NPB; i++) {
      float4 hv = *(const float4*)(h + (size_t)(node0 + i) * D + k);
      acc[i] += hv.x * w0 + hv.y * w1 + hv.z * w2 + hv.w * w3;
    }
  }
  float bv = bl[t];
  #pragma unroll
  for (int i = 0; i < NPB; i++)
    xl[(size_t)(node0 + i) * HC + t] = acc[i] + bv;
}

// ---- scores: ONE THREAD PER (EDGE, HEAD); writes w = exp(clamped score).
// R14 packed body; node-major xl addressing; head-clustered XCD mapping
// (per-XCD line working set = one head's 2.56MB of lines -> L2-resident).
__global__ __launch_bounds__(256) void k_score(
    const int* __restrict__ csr_src, const int* __restrict__ csr_dst,
    const float* __restrict__ ea_csr, const float* __restrict__ loop_attr,
    const float* __restrict__ xl, const float* __restrict__ Wpk,
    const float* __restrict__ att, float* __restrict__ wP) {
  int bid = blockIdx.x;                       // 0..TOTB-1
  int w = (bid & 7) * PERX + (bid >> 3);      // work item, contiguous per XCD
  int h = w / PB;                             // head (uniform, magic-div)
  int lb = w - h * PB;                        // p-slice within head
  int p = lb * 256 + threadIdx.x;
  if (p >= EF) return;
  int s, d;
  const float* ea;
  if (p < NE) { s = csr_src[p]; d = csr_dst[p]; ea = ea_csr + (size_t)p * ED; }
  else        { s = d = p - NE; ea = loop_attr + (size_t)(p - NE) * ED; }
  float eas[16];
  {
    const float4* q = (const float4*)ea;
    float4 t0 = q[0], t1 = q[1], t2 = q[2], t3 = q[3];
    eas[0] = t0.x;  eas[1] = t0.y;  eas[2] = t0.z;  eas[3] = t0.w;
    eas[4] = t1.x;  eas[5] = t1.y;  eas[6] = t1.z;  eas[7] = t1.w;
    eas[8] = t2.x;  eas[9] = t2.y;  eas[10] = t2.z; eas[11] = t2.w;
    eas[12] = t3.x; eas[13] = t3.y; eas[14] = t3.z; eas[15] = t3.w;
  }
  const float* xsrow = xl + (size_t)s * HC + h * CD;   // node-major
  const float* xdrow = xl + (size_t)d * HC + h * CD;
  const f2* wp = (const f2*)Wpk + (size_t)h * (CD / 2) * ED;  // [32 pairs][16 k]
  const f2* ap = (const f2*)(att + (size_t)h * CD);           // pairs contiguous
  f2 sc2 = {0.f, 0.f};
  const f2 zero = {0.f, 0.f};
  #pragma unroll 4
  for (int cb = 0; cb < CD; cb += 4) {  // 2 channel-pairs per iter, 16 iters
    int cp = cb >> 1;
    float4 xs4 = *(const float4*)(xsrow + cb);
    float4 xd4 = *(const float4*)(xdrow + cb);
    const f2* w0 = wp + (size_t)cp * ED;
    const f2* w1 = w0 + ED;
    f2 z0 = f2{xs4.x, xs4.y} + f2{xd4.x, xd4.y};   // v_pk_add_f32
    f2 z1 = f2{xs4.z, xs4.w} + f2{xd4.z, xd4.w};
    #pragma unroll
    for (int k = 0; k < ED; k++) {                 // 2x v_pk_fma_f32 per k
      z0 += w0[k] * eas[k];
      z1 += w1[k] * eas[k];
    }
    // leaky: max(z,0) + NEG*min(z,0)  (packed, branchless, exact)
    z0 = __builtin_elementwise_max(z0, zero) + NEG * __builtin_elementwise_min(z0, zero);
    z1 = __builtin_elementwise_max(z1, zero) + NEG * __builtin_elementwise_min(z1, zero);
    sc2 += z0 * ap[cp];
    sc2 += z1 * ap[cp + 1];
  }
  float sc = sc2.x + sc2.y;
  sc = fminf(fmaxf(sc, -60.f), 60.f);  // clamp never binds for sane inputs
  wP[(size_t)h * EFP + p] = __expf(sc);
}

// ---- aggregation: block per node, wave per head; fused head-mean+bias+ELU --
__global__ __launch_bounds__(320) void k_agg(
    const int* __restrict__ csr_src, const int* __restrict__ rowptr,
    const float* __restrict__ wP, const float* __restrict__ xl,
    const float* __restrict__ bias, float* __restrict__ out) {
  __shared__ float s_v[NH][CD];
  int h = threadIdx.x >> 6, lane = threadIdx.x & 63;
  int d = blockIdx.x;
  int b = rowptr[d], n = rowptr[d + 1] - b;
  const float* sp = wP + (size_t)h * EFP;
  const float* xlh = xl + h * CD + lane;               // node-major layout
  // self loop init
  float dn = sp[NE + d];
  float acc = dn * xlh[(size_t)d * HC];
  // edge loop, unroll 4 (uniform w addrs -> scalar loads)
  int p = b, pe = b + n;
  for (; p + 4 <= pe; p += 4) {
    int s0 = csr_src[p], s1 = csr_src[p + 1], s2 = csr_src[p + 2], s3 = csr_src[p + 3];
    float w0 = sp[p], w1 = sp[p + 1], w2 = sp[p + 2], w3 = sp[p + 3];
    float x0 = xlh[(size_t)s0 * HC];
    float x1 = xlh[(size_t)s1 * HC];
    float x2 = xlh[(size_t)s2 * HC];
    float x3 = xlh[(size_t)s3 * HC];
    dn += (w0 + w1) + (w2 + w3);
    acc += w0 * x0 + w1 * x1 + w2 * x2 + w3 * x3;
  }
  for (; p < pe; p++) {
    int s0 = csr_src[p];
    float w0 = sp[p];
    dn += w0;
    acc += w0 * xlh[(size_t)s0 * HC];
  }
  s_v[h][lane] = acc / dn;
  __syncthreads();
  if (h == 0) {
    float v = s_v[0][lane] + s_v[1][lane] + s_v[2][lane] + s_v[3][lane] + s_v[4][lane];
    v = v * (1.0f / NH) + bias[lane];
    v = v > 0.f ? v : expm1f(v);
    out[(size_t)d * CD + lane] = v;
  }
}

static inline size_t aln(size_t x) { return (x + 255) & ~(size_t)255; }

extern "C" void kernel_launch(void* const* d_in, const int* in_sizes, int n_in,
                              void* d_out, int out_size, void* d_ws, size_t ws_size,
                              hipStream_t stream) {
  const float* x = (const float*)d_in[0];
  const int* ei = (const int*)d_in[1];      // [2, NE]: src row then dst row
  const float* eattr = (const float*)d_in[2];

  char* w = (char*)d_ws;
  int* degi      = (int*)w;                 w += aln(NN * 4);
  int* cursor    = (int*)w;                 w += aln(NN * 4);
  int* rowptr    = (int*)w;                 w += aln((NN + 1) * 4);
  int* csr_eid   = (int*)w;                 w += aln((size_t)NE * 4);
  int* csr_src   = (int*)w;                 w += aln((size_t)NE * 4);
  int* csr_dst   = (int*)w;                 w += aln((size_t)NE * 4);
  float* loop_attr = (float*)w;             w += aln((size_t)NN * ED * 4);
  float* ea_csr  = (float*)w;               w += aln((size_t)NE * ED * 4);
  float* xl      = (float*)w;               w += aln((size_t)NN * HC * 4);
  float* wPbuf   = (float*)w;               w += aln((size_t)NH * EFP * 4);
  float* Wpk     = (float*)w;               w += aln((size_t)ED * HC * 4);
  float* hbuf    = (float*)w;               w += aln((size_t)NN * CD * 4);

  // graph structure + permuted edge attrs (layer-invariant)
  hipMemsetAsync(degi, 0, NN * 4, stream);
  hipMemsetAsync(cursor, 0, NN * 4, stream);
  k_count<<<(NE + 255) / 256, 256, 0, stream>>>(ei + NE, degi);
  k_scan<<<1, 1024, 0, stream>>>(degi, rowptr);
  k_fill<<<(NE + 255) / 256, 256, 0, stream>>>(ei, rowptr, cursor, csr_eid, csr_src, csr_dst);
  k_eacsr<<<(NE * 4 + 255) / 256, 256, 0, stream>>>(csr_eid, eattr, ea_csr);
  k_loopattr<<<(NN + 3) / 4, 256, 0, stream>>>(ea_csr, rowptr, loop_attr);

  for (int l = 0; l < 3; l++) {
    const float* Wl  = (const float*)d_in[3 + 5 * l];
    const float* bl  = (const float*)d_in[4 + 5 * l];
    const float* We  = (const float*)d_in[5 + 5 * l];
    const float* att = (const float*)d_in[6 + 5 * l];
    const float* b   = (const float*)d_in[7 + 5 * l];

    k_wet<<<(ED * HC + 255) / 256, 256, 0, stream>>>(We, Wpk);
    if (l == 0) k_xl<ND><<<NN / 8, 320, 0, stream>>>(x, Wl, bl, xl);
    else        k_xl<CD><<<NN / 8, 320, 0, stream>>>(hbuf, Wl, bl, xl);

    k_score<<<TOTB, 256, 0, stream>>>(csr_src, csr_dst, ea_csr, loop_attr,
                                      xl, Wpk, att, wPbuf);

    float* dst_out = (l < 2) ? hbuf : (float*)d_out;
    k_agg<<<NN, 320, 0, stream>>>(csr_src, rowptr, wPbuf, xl, b, dst_out);
  }
}